// Round 3
// baseline (466.976 us; speedup 1.0000x reference)
//
#include <hip/hip_runtime.h>

// ---------------------------------------------------------------- constants
#define T_N   262144
#define D_IN  128
#define H_HID 256
#define A_DIM 8
#define GAMMA 0.99f
#define EPS_C 0.2f
#define C_GL  0.9405f                 // GAMMA*LMBD
#define HALF_LOG_2PI 0.9189385332f
#define CR_TPB 16                     // critic tiles per block (32 rows each)
#define AC_TPB 8                      // actor tiles per block

typedef __attribute__((ext_vector_type(8))) short short8;
typedef __attribute__((ext_vector_type(4))) float f32x4;

__device__ __forceinline__ unsigned short f2bf(float f) {
  unsigned int u = __float_as_uint(f);
  u += 0x7FFFu + ((u >> 16) & 1u);          // RNE
  return (unsigned short)(u >> 16);
}
__device__ __forceinline__ float fast_tanh(float x) {
  x = fminf(10.f, fmaxf(-10.f, x));
  float e = __expf(2.f * x);
  return 1.f - 2.f * __builtin_amdgcn_rcpf(e + 1.f);
}

// ---------------------------------------------------------------- prep:
// Wc1T/W1T: [H][D] bf16 (transposed, n-major) for B-fragments.
// H1: [16][256] bf16 actor head weights (rows0-7 = Wmu^T, 8-15 = Wlv^T)
__global__ __launch_bounds__(256) void k_prep(
    const float* __restrict__ Wc1, const float* __restrict__ W1,
    const float* __restrict__ Wmu, const float* __restrict__ Wlv,
    unsigned short* __restrict__ Wc1T, unsigned short* __restrict__ W1T,
    unsigned short* __restrict__ H1) {
  int i = blockIdx.x * 256 + threadIdx.x;
  if (i < 32768) {
    int n = i >> 7, k = i & 127;
    Wc1T[i] = f2bf(Wc1[k * 256 + n]);
  } else if (i < 65536) {
    int j = i - 32768; int n = j >> 7, k = j & 127;
    W1T[j] = f2bf(W1[k * 256 + n]);
  } else if (i < 69632) {
    int j = i - 65536; int h = j >> 8, n = j & 255;
    H1[j] = (h < 8) ? f2bf(Wmu[n * 8 + h]) : f2bf(Wlv[n * 8 + (h - 8)]);
  }
}

// ---------------------------------------------------------------- critic:
// persistent pipelined blocks. 1024 blocks x CR_TPB tiles of 32 rows.
// tile T: job = T>>13 (0=state->v0, 1=next->v1), r0 = (T&8191)*32.
// Both jobs share Wc1 -> bfrag loaded once per block lifetime.
// Pipeline: [store staged regs -> LDS; barrier; prefetch next tile -> regs;
//            MFMA + fused head epilogue; barrier; write v].
__global__ __launch_bounds__(256, 4) void k_critic(
    const float* __restrict__ state, const float* __restrict__ next_state,
    const unsigned short* __restrict__ Wc1T,
    const float* __restrict__ bc1, const float* __restrict__ Wc2,
    const float* __restrict__ bc2,
    float* __restrict__ v0out, float* __restrict__ v1out) {
  const int tid = threadIdx.x;
  const int lane = tid & 63;
  const int wv   = tid >> 6;
  const int c    = lane & 15;
  const int quad = lane >> 4;

  __shared__ unsigned short sh_x[32 * 136];    // 8.5 KB
  __shared__ float sh_v[32 * 4];

  // ---- B fragments + bias + head weights: once per block
  short8 bfrag[4][4];
  float bias_c[4], wc2_c[4];
#pragma unroll
  for (int ct = 0; ct < 4; ++ct) {
    int n = wv * 64 + ct * 16 + c;
    bias_c[ct] = bc1[n];
    wc2_c[ct]  = Wc2[n];
#pragma unroll
    for (int ki = 0; ki < 4; ++ki)
      bfrag[ct][ki] = *(const short8*)(Wc1T + n * 128 + ki * 32 + quad * 8);
  }
  const float vbias = bc2[0];

  const int t0 = blockIdx.x * CR_TPB;

  // ---- prologue: stage tile t0 into regs
  float4 rbuf[4];
  {
    const float* X = (t0 >> 13) ? next_state : state;
    const float4* Xv = (const float4*)(X + (t0 & 8191) * 32 * D_IN);
#pragma unroll
    for (int j = 0; j < 4; ++j) rbuf[j] = Xv[tid + j * 256];
  }

  for (int i = 0; i < CR_TPB; ++i) {
    const int T = t0 + i;
    const int job = T >> 13;
    const int r0  = (T & 8191) * 32;

    // ---- regs -> LDS bf16
#pragma unroll
    for (int j = 0; j < 4; ++j) {
      int e = tid + j * 256;
      int row = e >> 5, c4 = e & 31;
      ushort4 u;
      u.x = f2bf(rbuf[j].x); u.y = f2bf(rbuf[j].y);
      u.z = f2bf(rbuf[j].z); u.w = f2bf(rbuf[j].w);
      *(ushort4*)(&sh_x[row * 136 + c4 * 4]) = u;
    }
    __syncthreads();

    // ---- prefetch next tile (issue now, overlap with compute below)
    if (i + 1 < CR_TPB) {
      int T2 = T + 1;
      const float* X2 = (T2 >> 13) ? next_state : state;
      const float4* Xv2 = (const float4*)(X2 + (T2 & 8191) * 32 * D_IN);
#pragma unroll
      for (int j = 0; j < 4; ++j) rbuf[j] = Xv2[tid + j * 256];
    }

    // ---- GEMM + fused critic head (2 row-tiles of 16)
#pragma unroll
    for (int rt = 0; rt < 2; ++rt) {
      f32x4 acc[4];
#pragma unroll
      for (int ct = 0; ct < 4; ++ct) acc[ct] = (f32x4){0.f, 0.f, 0.f, 0.f};
#pragma unroll
      for (int ki = 0; ki < 4; ++ki) {
        short8 a = *(const short8*)(&sh_x[(rt * 16 + c) * 136 + ki * 32 + quad * 8]);
#pragma unroll
        for (int ct = 0; ct < 4; ++ct)
          acc[ct] = __builtin_amdgcn_mfma_f32_16x16x32_bf16(a, bfrag[ct][ki], acc[ct], 0, 0, 0);
      }
#pragma unroll
      for (int r = 0; r < 4; ++r) {
        float p = 0.f;
#pragma unroll
        for (int ct = 0; ct < 4; ++ct)
          p += fast_tanh(acc[ct][r] + bias_c[ct]) * wc2_c[ct];
        p += __shfl_xor(p, 1);
        p += __shfl_xor(p, 2);
        p += __shfl_xor(p, 4);
        p += __shfl_xor(p, 8);
        if (c == 0) sh_v[(rt * 16 + quad * 4 + r) * 4 + wv] = p;
      }
    }
    __syncthreads();
    if (tid < 32) {
      float* out = job ? v1out : v0out;
      out[r0 + tid] = sh_v[tid * 4] + sh_v[tid * 4 + 1] + sh_v[tid * 4 + 2] +
                      sh_v[tid * 4 + 3] + vbias;
    }
  }
}

// ---------------------------------------------------------------- actor:
// persistent pipelined blocks. 1024 blocks x AC_TPB tiles of 32 rows of state.
__global__ __launch_bounds__(256, 4) void k_actor(
    const float* __restrict__ state,
    const float* __restrict__ action, const float* __restrict__ beta_lp,
    const unsigned short* __restrict__ W1T, const unsigned short* __restrict__ H1,
    const float* __restrict__ b1, const float* __restrict__ bmu,
    const float* __restrict__ blv,
    float* __restrict__ ratio) {
  const int tid = threadIdx.x;
  const int lane = tid & 63;
  const int wv   = tid >> 6;
  const int c    = lane & 15;
  const int quad = lane >> 4;

  __shared__ unsigned short sh_x[32 * 136];    // 8.5 KB
  __shared__ unsigned short sh_h[32 * 264];    // 16.5 KB
  __shared__ float sh_hb[4 * 32 * 16];         // [wave][sample][head] 8 KB

  short8 bfrag[4][4];
  float bias_c[4];
#pragma unroll
  for (int ct = 0; ct < 4; ++ct) {
    int n = wv * 64 + ct * 16 + c;
    bias_c[ct] = b1[n];
#pragma unroll
    for (int ki = 0; ki < 4; ++ki)
      bfrag[ct][ki] = *(const short8*)(W1T + n * 128 + ki * 32 + quad * 8);
  }
  const int aa = tid & 7;                      // tail action index
  const float bmu_a = bmu[aa], blv_a = blv[aa];

  const int t0 = blockIdx.x * AC_TPB;

  float4 rbuf[4];
  {
    const float4* Xv = (const float4*)(state + t0 * 32 * D_IN);
#pragma unroll
    for (int j = 0; j < 4; ++j) rbuf[j] = Xv[tid + j * 256];
  }

  for (int i = 0; i < AC_TPB; ++i) {
    const int r0 = (t0 + i) * 32;

#pragma unroll
    for (int j = 0; j < 4; ++j) {
      int e = tid + j * 256;
      int row = e >> 5, c4 = e & 31;
      ushort4 u;
      u.x = f2bf(rbuf[j].x); u.y = f2bf(rbuf[j].y);
      u.z = f2bf(rbuf[j].z); u.w = f2bf(rbuf[j].w);
      *(ushort4*)(&sh_x[row * 136 + c4 * 4]) = u;
    }
    __syncthreads();

    if (i + 1 < AC_TPB) {
      const float4* Xv2 = (const float4*)(state + (r0 + 32) * D_IN);
#pragma unroll
      for (int j = 0; j < 4; ++j) rbuf[j] = Xv2[tid + j * 256];
    }

    // ---- main GEMM: 2 row-tiles, epilogue -> sh_h
#pragma unroll
    for (int rt = 0; rt < 2; ++rt) {
      f32x4 acc[4];
#pragma unroll
      for (int ct = 0; ct < 4; ++ct) acc[ct] = (f32x4){0.f, 0.f, 0.f, 0.f};
#pragma unroll
      for (int ki = 0; ki < 4; ++ki) {
        short8 a = *(const short8*)(&sh_x[(rt * 16 + c) * 136 + ki * 32 + quad * 8]);
#pragma unroll
        for (int ct = 0; ct < 4; ++ct)
          acc[ct] = __builtin_amdgcn_mfma_f32_16x16x32_bf16(a, bfrag[ct][ki], acc[ct], 0, 0, 0);
      }
#pragma unroll
      for (int ct = 0; ct < 4; ++ct) {
        int col = wv * 64 + ct * 16 + c;
#pragma unroll
        for (int r = 0; r < 4; ++r) {
          int row = rt * 16 + quad * 4 + r;
          sh_h[row * 264 + col] = f2bf(fast_tanh(acc[ct][r] + bias_c[ct]));
        }
      }
    }
    __syncthreads();

    // ---- head GEMM: wave wv handles its own K-slice (cols wv*64..+63),
    //      two 16-sample tiles; partials -> sh_hb[wv]
#pragma unroll
    for (int st = 0; st < 2; ++st) {
      f32x4 acc2 = (f32x4){0.f, 0.f, 0.f, 0.f};
#pragma unroll
      for (int k2 = 0; k2 < 2; ++k2) {
        int kofs = wv * 64 + k2 * 32 + quad * 8;
        short8 a2 = *(const short8*)(H1 + c * 256 + kofs);                 // A[head=c][k]
        short8 b2 = *(const short8*)(&sh_h[(st * 16 + c) * 264 + kofs]);   // B[k][sample=c]
        acc2 = __builtin_amdgcn_mfma_f32_16x16x32_bf16(a2, b2, acc2, 0, 0, 0);
      }
      // D: head=quad*4+r, sample=st*16+c
      *((f32x4*)&sh_hb[((wv * 32) + st * 16 + c) * 16 + quad * 4]) = acc2;
    }
    __syncthreads();

    // ---- tail: thread -> (sample=tid>>3, action=tid&7)
    {
      int s = tid >> 3;
      int t = r0 + s;
      float mu = sh_hb[(s)*16 + aa]     + sh_hb[(32 + s) * 16 + aa] +
                 sh_hb[(64 + s) * 16 + aa] + sh_hb[(96 + s) * 16 + aa] + bmu_a;
      float lv = sh_hb[(s)*16 + 8 + aa]     + sh_hb[(32 + s) * 16 + 8 + aa] +
                 sh_hb[(64 + s) * 16 + 8 + aa] + sh_hb[(96 + s) * 16 + 8 + aa] + blv_a;
      float ac = action[t * A_DIM + aa];
      float bl = beta_lp[t * A_DIM + aa];
      float d = ac - mu;
      float term = -0.5f * d * d * __expf(-lv) - 0.5f * lv - HALF_LOG_2PI - bl;
      term += __shfl_xor(term, 1);
      term += __shfl_xor(term, 2);
      term += __shfl_xor(term, 4);
      if (aa == 0) ratio[t] = __expf(term);
    }
  }
}

// ---------------------------------------------------------------- GAE, one kernel:
// 256 blocks x 1024 own elems; each block also reads 1024 lookahead
// (c^1024 ~ 5e-28 -> truncation below fp32 ulp).
__global__ __launch_bounds__(256) void k_gae(
    const float* __restrict__ reward, const float* __restrict__ v0,
    const float* __restrict__ v1, float* __restrict__ adv,
    float* __restrict__ accs) {
  const int j = blockIdx.x, k = threadIdx.x;
  const int base = j * 1024 + k * 8;
  float d[8];
  float s = 0.f, w = 1.f;
#pragma unroll
  for (int i = 0; i < 8; ++i) {
    int idx = base + i;
    float dd = 0.f;
    if (idx < T_N) dd = reward[idx] + GAMMA * v1[idx] - v0[idx];
    d[i] = dd;
    s += w * dd;
    w *= C_GL;
  }
  const float W8 = w;
  __shared__ float Ss[256], Sw[256];
  Ss[k] = s; Sw[k] = W8;
  __syncthreads();
  for (int dd = 1; dd < 256; dd <<= 1) {
    bool has = (k + dd) < 256;
    float ns = 0.f, nw = 0.f;
    if (has) { ns = Ss[k] + Sw[k] * Ss[k + dd]; nw = Sw[k] * Sw[k + dd]; }
    __syncthreads();
    if (has) { Ss[k] = ns; Sw[k] = nw; }
    __syncthreads();
  }
  float g = (k < 255) ? Ss[k + 1] : 0.f;
  float sa = 0.f, sq = 0.f;
  if (k < 128) {
#pragma unroll
    for (int i = 7; i >= 0; --i) {
      g = d[i] + C_GL * g;
      float a = g - v0[base + i];
      adv[base + i] = a;
      sa += a; sq += a * a;
    }
  }
  __syncthreads();
  Ss[k] = sa; Sw[k] = sq;
  __syncthreads();
  for (int off = 128; off > 0; off >>= 1) {
    if (k < off) { Ss[k] += Ss[k + off]; Sw[k] += Sw[k + off]; }
    __syncthreads();
  }
  if (k == 0) {
    atomicAdd(&accs[0], Ss[0]);                 // Σ adv
    atomicAdd(&accs[1], Sw[0]);                 // Σ adv² (= critic_loss)
  }
}

// ---------------------------------------------------------------- actor loss (+ final sum, last-block)
__global__ __launch_bounds__(256) void k_loss(
    const float* __restrict__ adv, const float* __restrict__ ratio,
    float* __restrict__ accs, float* __restrict__ out) {
  int t = blockIdx.x * 256 + threadIdx.x;
  float sum  = accs[0];
  float mean = sum * (1.f / (float)T_N);
  float var  = (accs[1] - sum * mean) / (float)(T_N - 1);
  float inv  = 1.f / (sqrtf(var) + 1e-7f);
  float a = (adv[t] - mean) * inv;
  float r = ratio[t];
  float rc = fminf(fmaxf(r, 1.f - EPS_C), 1.f + EPS_C);
  float term = -fminf(r * a, rc * a);
  __shared__ float red[256];
  int k = threadIdx.x;
  red[k] = term;
  __syncthreads();
  for (int off = 128; off > 0; off >>= 1) {
    if (k < off) red[k] += red[k + off];
    __syncthreads();
  }
  if (k == 0) {
    atomicAdd(&accs[2], red[0]);
    __threadfence();
    unsigned int old = atomicAdd((unsigned int*)&accs[3], 1u);
    if (old == (unsigned int)(gridDim.x - 1)) {
      __threadfence();
      volatile float* va = (volatile float*)accs;
      out[0] = va[2] + va[1];                   // actor_loss + critic_loss
    }
  }
}

// ---------------------------------------------------------------- launch
extern "C" void kernel_launch(void* const* d_in, const int* in_sizes, int n_in,
                              void* d_out, int out_size, void* d_ws, size_t ws_size,
                              hipStream_t stream) {
  const float* state      = (const float*)d_in[0];
  const float* next_state = (const float*)d_in[1];
  const float* action     = (const float*)d_in[2];
  const float* beta_lp    = (const float*)d_in[3];
  const float* reward     = (const float*)d_in[4];
  const float* W1   = (const float*)d_in[5];
  const float* b1   = (const float*)d_in[6];
  const float* Wmu  = (const float*)d_in[7];
  const float* bmu  = (const float*)d_in[8];
  const float* Wlv  = (const float*)d_in[9];
  const float* blv  = (const float*)d_in[10];
  const float* Wc1  = (const float*)d_in[11];
  const float* bc1  = (const float*)d_in[12];
  const float* Wc2  = (const float*)d_in[13];
  const float* bc2  = (const float*)d_in[14];

  char* ws = (char*)d_ws;
  size_t o = 0;
  unsigned short* Wc1T = (unsigned short*)(ws + o); o += 65536;
  unsigned short* W1T  = (unsigned short*)(ws + o); o += 65536;
  unsigned short* H1   = (unsigned short*)(ws + o); o += 8192;
  float* v0    = (float*)(ws + o); o += (size_t)T_N * 4;
  float* v1    = (float*)(ws + o); o += (size_t)T_N * 4;
  float* ratio = (float*)(ws + o); o += (size_t)T_N * 4;
  float* adv   = (float*)(ws + o); o += (size_t)T_N * 4;
  float* accs  = (float*)(ws + o); o += 256;

  hipMemsetAsync(accs, 0, 32, stream);

  k_prep<<<272, 256, 0, stream>>>(Wc1, W1, Wmu, Wlv, Wc1T, W1T, H1);

  k_critic<<<(2 * T_N / 32) / CR_TPB, 256, 0, stream>>>(
      state, next_state, Wc1T, bc1, Wc2, bc2, v0, v1);
  k_actor<<<(T_N / 32) / AC_TPB, 256, 0, stream>>>(
      state, action, beta_lp, W1T, H1, b1, bmu, blv, ratio);
  k_gae<<<256, 256, 0, stream>>>(reward, v0, v1, adv, accs);
  k_loss<<<T_N / 256, 256, 0, stream>>>(adv, ratio, accs, (float*)d_out);
}

// Round 4
// 383.068 us; speedup vs baseline: 1.2190x; 1.2190x over previous
//
#include <hip/hip_runtime.h>

// ---------------------------------------------------------------- constants
#define T_N   262144
#define D_IN  128
#define H_HID 256
#define A_DIM 8
#define GAMMA 0.99f
#define EPS_C 0.2f
#define C_GL  0.9405f                 // GAMMA*LMBD
#define HALF_LOG_2PI 0.9189385332f
#define SCALE2 2.8853900817779268f    // 2*log2(e): pre-activation scale for exp2-tanh
#define ST_TPB 16                     // k_state tiles per block (32 rows each)
#define NX_TPB 8                      // k_next tiles per block

typedef __attribute__((ext_vector_type(8))) short short8;
typedef __attribute__((ext_vector_type(4))) float f32x4;

__device__ __forceinline__ unsigned short f2bf(float f) {
  unsigned int u = __float_as_uint(f);
  u += 0x7FFFu + ((u >> 16) & 1u);          // RNE
  return (unsigned short)(u >> 16);
}
// a = 2*log2(e)*x (weights pre-scaled); returns tanh(x). No clamp needed:
// exp2(+inf)->inf -> rcp->0 -> 1 ; exp2(-big)->0 -> rcp(1)=1 -> -1.
__device__ __forceinline__ float tanh_pre(float a) {
  float e = __builtin_amdgcn_exp2f(a);
  return 1.f - 2.f * __builtin_amdgcn_rcpf(e + 1.f);
}
// sum over 16-lane DPP rows via inclusive row_shr scan; total at lane%16==15.
__device__ __forceinline__ float row16_sum(float p) {
  p += __int_as_float(__builtin_amdgcn_update_dpp(0, __float_as_int(p), 0x111, 0xf, 0xf, true));
  p += __int_as_float(__builtin_amdgcn_update_dpp(0, __float_as_int(p), 0x112, 0xf, 0xf, true));
  p += __int_as_float(__builtin_amdgcn_update_dpp(0, __float_as_int(p), 0x114, 0xf, 0xf, true));
  p += __int_as_float(__builtin_amdgcn_update_dpp(0, __float_as_int(p), 0x118, 0xf, 0xf, true));
  return p;
}

// ---------------------------------------------------------------- prep:
// Wc1Ts/W1Ts: [H][D] bf16, transposed AND pre-scaled by 2*log2(e).
// H1: [16][256] bf16 actor head weights (rows0-7 = Wmu^T, 8-15 = Wlv^T), unscaled.
__global__ __launch_bounds__(256) void k_prep(
    const float* __restrict__ Wc1, const float* __restrict__ W1,
    const float* __restrict__ Wmu, const float* __restrict__ Wlv,
    unsigned short* __restrict__ Wc1Ts, unsigned short* __restrict__ W1Ts,
    unsigned short* __restrict__ H1) {
  int i = blockIdx.x * 256 + threadIdx.x;
  if (i < 32768) {
    int n = i >> 7, k = i & 127;
    Wc1Ts[i] = f2bf(Wc1[k * 256 + n] * SCALE2);
  } else if (i < 65536) {
    int j = i - 32768; int n = j >> 7, k = j & 127;
    W1Ts[j] = f2bf(W1[k * 256 + n] * SCALE2);
  } else if (i < 69632) {
    int j = i - 65536; int h = j >> 8, n = j & 255;
    H1[j] = (h < 8) ? f2bf(Wmu[n * 8 + h]) : f2bf(Wlv[n * 8 + (h - 8)]);
  }
}

// ---------------------------------------------------------------- k_state:
// 512-thread persistent blocks; waves 0-3 = critic(state)->v0 slice,
// waves 4-7 = actor(state)->ratio slice. One shared X tile per iteration.
__global__ __launch_bounds__(512, 4) void k_state(
    const float* __restrict__ state,
    const float* __restrict__ action, const float* __restrict__ beta_lp,
    const unsigned short* __restrict__ Wc1Ts, const unsigned short* __restrict__ W1Ts,
    const unsigned short* __restrict__ H1,
    const float* __restrict__ bc1, const float* __restrict__ b1,
    const float* __restrict__ Wc2, const float* __restrict__ bc2,
    const float* __restrict__ bmu, const float* __restrict__ blv,
    float* __restrict__ v0out, float* __restrict__ ratio) {
  const int tid  = threadIdx.x;
  const int lane = tid & 63;
  const int wv   = tid >> 6;          // 0..7
  const int role = wv >> 2;           // 0 = critic, 1 = actor
  const int wl   = wv & 3;            // slice id within role
  const int c    = lane & 15;
  const int quad = lane >> 4;

  __shared__ unsigned short sh_x[32 * 136];   // 8.5 KB
  __shared__ unsigned short sh_h[32 * 264];   // 16.5 KB
  __shared__ float sh_hb[4 * 32 * 16];        // [slice][sample][head] 8 KB
  __shared__ float sh_v[32 * 4];

  const unsigned short* WT = role ? W1Ts : Wc1Ts;
  const float* bias = role ? b1 : bc1;

  short8 bfrag[4][4];
  float bias_c[4], wc2_c[4];
#pragma unroll
  for (int ct = 0; ct < 4; ++ct) {
    int n = wl * 64 + ct * 16 + c;
    bias_c[ct] = bias[n] * SCALE2;
    wc2_c[ct]  = Wc2[n];
#pragma unroll
    for (int ki = 0; ki < 4; ++ki)
      bfrag[ct][ki] = *(const short8*)(WT + n * 128 + ki * 32 + quad * 8);
  }
  const float vbias = bc2[0];
  const int aa = tid & 7;
  const float bmu_a = bmu[aa], blv_a = blv[aa];

  const int t0 = blockIdx.x * ST_TPB;

  float4 rbuf[2];
  {
    const float4* Xv = (const float4*)(state + t0 * 32 * D_IN);
    rbuf[0] = Xv[tid]; rbuf[1] = Xv[tid + 512];
  }

  for (int i = 0; i < ST_TPB; ++i) {
    const int r0 = (t0 + i) * 32;

    // ---- regs -> LDS bf16 (32 rows x 128)
#pragma unroll
    for (int j = 0; j < 2; ++j) {
      int e4 = tid + j * 512;
      int row = e4 >> 5, c4 = e4 & 31;
      ushort4 u;
      u.x = f2bf(rbuf[j].x); u.y = f2bf(rbuf[j].y);
      u.z = f2bf(rbuf[j].z); u.w = f2bf(rbuf[j].w);
      *(ushort4*)(&sh_x[row * 136 + c4 * 4]) = u;
    }
    __syncthreads();                            // barrier1

    // ---- prefetch next X tile + this tile's action/beta
    if (i + 1 < ST_TPB) {
      const float4* Xv2 = (const float4*)(state + (r0 + 32) * D_IN);
      rbuf[0] = Xv2[tid]; rbuf[1] = Xv2[tid + 512];
    }
    float fa = 0.f, fb = 0.f;
    if (tid < 256) { fa = action[r0 * 8 + tid]; fb = beta_lp[r0 * 8 + tid]; }

    if (role == 0) {
      // ---- critic GEMM + fused head (2 row-tiles of 16)
#pragma unroll
      for (int rt = 0; rt < 2; ++rt) {
        f32x4 acc[4];
#pragma unroll
        for (int ct = 0; ct < 4; ++ct) acc[ct] = (f32x4){0.f, 0.f, 0.f, 0.f};
#pragma unroll
        for (int ki = 0; ki < 4; ++ki) {
          short8 a = *(const short8*)(&sh_x[(rt * 16 + c) * 136 + ki * 32 + quad * 8]);
#pragma unroll
          for (int ct = 0; ct < 4; ++ct)
            acc[ct] = __builtin_amdgcn_mfma_f32_16x16x32_bf16(a, bfrag[ct][ki], acc[ct], 0, 0, 0);
        }
#pragma unroll
        for (int r = 0; r < 4; ++r) {
          float p = 0.f;
#pragma unroll
          for (int ct = 0; ct < 4; ++ct)
            p += tanh_pre(acc[ct][r] + bias_c[ct]) * wc2_c[ct];
          p = row16_sum(p);
          if (c == 15) sh_v[(rt * 16 + quad * 4 + r) * 4 + wl] = p;
        }
      }
    } else {
      // ---- actor GEMM, epilogue -> sh_h
#pragma unroll
      for (int rt = 0; rt < 2; ++rt) {
        f32x4 acc[4];
#pragma unroll
        for (int ct = 0; ct < 4; ++ct) acc[ct] = (f32x4){0.f, 0.f, 0.f, 0.f};
#pragma unroll
        for (int ki = 0; ki < 4; ++ki) {
          short8 a = *(const short8*)(&sh_x[(rt * 16 + c) * 136 + ki * 32 + quad * 8]);
#pragma unroll
          for (int ct = 0; ct < 4; ++ct)
            acc[ct] = __builtin_amdgcn_mfma_f32_16x16x32_bf16(a, bfrag[ct][ki], acc[ct], 0, 0, 0);
        }
#pragma unroll
        for (int ct = 0; ct < 4; ++ct) {
          int col = wl * 64 + ct * 16 + c;
#pragma unroll
          for (int r = 0; r < 4; ++r) {
            int row = rt * 16 + quad * 4 + r;
            sh_h[row * 264 + col] = f2bf(tanh_pre(acc[ct][r] + bias_c[ct]));
          }
        }
      }
    }
    __syncthreads();                            // barrier2: sh_h, sh_v ready

    if (role == 1) {
      // ---- head GEMM: slice wl owns K-cols [wl*64, wl*64+64)
#pragma unroll
      for (int st = 0; st < 2; ++st) {
        f32x4 acc2 = (f32x4){0.f, 0.f, 0.f, 0.f};
#pragma unroll
        for (int k2 = 0; k2 < 2; ++k2) {
          int kofs = wl * 64 + k2 * 32 + quad * 8;
          short8 a2 = *(const short8*)(H1 + c * 256 + kofs);
          short8 b2 = *(const short8*)(&sh_h[(st * 16 + c) * 264 + kofs]);
          acc2 = __builtin_amdgcn_mfma_f32_16x16x32_bf16(a2, b2, acc2, 0, 0, 0);
        }
        *((f32x4*)&sh_hb[((wl * 32) + st * 16 + c) * 16 + quad * 4]) = acc2;
      }
    } else if (tid < 32) {
      v0out[r0 + tid] = sh_v[tid * 4] + sh_v[tid * 4 + 1] + sh_v[tid * 4 + 2] +
                        sh_v[tid * 4 + 3] + vbias;
    }
    __syncthreads();                            // barrier3: sh_hb ready

    if (tid < 256) {
      int s = tid >> 3;
      float mu = sh_hb[(s)*16 + aa]          + sh_hb[(32 + s) * 16 + aa] +
                 sh_hb[(64 + s) * 16 + aa]   + sh_hb[(96 + s) * 16 + aa] + bmu_a;
      float lv = sh_hb[(s)*16 + 8 + aa]      + sh_hb[(32 + s) * 16 + 8 + aa] +
                 sh_hb[(64 + s) * 16 + 8 + aa] + sh_hb[(96 + s) * 16 + 8 + aa] + blv_a;
      float d = fa - mu;
      float term = -0.5f * d * d * __expf(-lv) - 0.5f * lv - HALF_LOG_2PI - fb;
      term += __shfl_xor(term, 1);
      term += __shfl_xor(term, 2);
      term += __shfl_xor(term, 4);
      if (aa == 0) ratio[r0 + s] = __expf(term);
    }
  }
}

// ---------------------------------------------------------------- k_next:
// critic(next_state) -> v1. 256-thread persistent pipelined blocks.
__global__ __launch_bounds__(256, 4) void k_next(
    const float* __restrict__ next_state,
    const unsigned short* __restrict__ Wc1Ts,
    const float* __restrict__ bc1, const float* __restrict__ Wc2,
    const float* __restrict__ bc2, float* __restrict__ v1out) {
  const int tid = threadIdx.x;
  const int lane = tid & 63;
  const int wv   = tid >> 6;
  const int c    = lane & 15;
  const int quad = lane >> 4;

  __shared__ unsigned short sh_x[32 * 136];
  __shared__ float sh_v[32 * 4];

  short8 bfrag[4][4];
  float bias_c[4], wc2_c[4];
#pragma unroll
  for (int ct = 0; ct < 4; ++ct) {
    int n = wv * 64 + ct * 16 + c;
    bias_c[ct] = bc1[n] * SCALE2;
    wc2_c[ct]  = Wc2[n];
#pragma unroll
    for (int ki = 0; ki < 4; ++ki)
      bfrag[ct][ki] = *(const short8*)(Wc1Ts + n * 128 + ki * 32 + quad * 8);
  }
  const float vbias = bc2[0];

  const int t0 = blockIdx.x * NX_TPB;
  float4 rbuf[4];
  {
    const float4* Xv = (const float4*)(next_state + t0 * 32 * D_IN);
#pragma unroll
    for (int j = 0; j < 4; ++j) rbuf[j] = Xv[tid + j * 256];
  }

  for (int i = 0; i < NX_TPB; ++i) {
    const int r0 = (t0 + i) * 32;
#pragma unroll
    for (int j = 0; j < 4; ++j) {
      int e = tid + j * 256;
      int row = e >> 5, c4 = e & 31;
      ushort4 u;
      u.x = f2bf(rbuf[j].x); u.y = f2bf(rbuf[j].y);
      u.z = f2bf(rbuf[j].z); u.w = f2bf(rbuf[j].w);
      *(ushort4*)(&sh_x[row * 136 + c4 * 4]) = u;
    }
    __syncthreads();

    if (i + 1 < NX_TPB) {
      const float4* Xv2 = (const float4*)(next_state + (r0 + 32) * D_IN);
#pragma unroll
      for (int j = 0; j < 4; ++j) rbuf[j] = Xv2[tid + j * 256];
    }

#pragma unroll
    for (int rt = 0; rt < 2; ++rt) {
      f32x4 acc[4];
#pragma unroll
      for (int ct = 0; ct < 4; ++ct) acc[ct] = (f32x4){0.f, 0.f, 0.f, 0.f};
#pragma unroll
      for (int ki = 0; ki < 4; ++ki) {
        short8 a = *(const short8*)(&sh_x[(rt * 16 + c) * 136 + ki * 32 + quad * 8]);
#pragma unroll
        for (int ct = 0; ct < 4; ++ct)
          acc[ct] = __builtin_amdgcn_mfma_f32_16x16x32_bf16(a, bfrag[ct][ki], acc[ct], 0, 0, 0);
      }
#pragma unroll
      for (int r = 0; r < 4; ++r) {
        float p = 0.f;
#pragma unroll
        for (int ct = 0; ct < 4; ++ct)
          p += tanh_pre(acc[ct][r] + bias_c[ct]) * wc2_c[ct];
        p = row16_sum(p);
        if (c == 15) sh_v[(rt * 16 + quad * 4 + r) * 4 + wv] = p;
      }
    }
    __syncthreads();
    if (tid < 32) {
      v1out[r0 + tid] = sh_v[tid * 4] + sh_v[tid * 4 + 1] + sh_v[tid * 4 + 2] +
                        sh_v[tid * 4 + 3] + vbias;
    }
  }
}

// ---------------------------------------------------------------- GAE, one kernel:
// 256 blocks x 1024 own elems; each also reads 1024 lookahead
// (c^1024 ~ 5e-28 -> truncation below fp32 ulp).
__global__ __launch_bounds__(256) void k_gae(
    const float* __restrict__ reward, const float* __restrict__ v0,
    const float* __restrict__ v1, float* __restrict__ adv,
    float* __restrict__ accs) {
  const int j = blockIdx.x, k = threadIdx.x;
  const int base = j * 1024 + k * 8;
  float d[8];
  float s = 0.f, w = 1.f;
#pragma unroll
  for (int i = 0; i < 8; ++i) {
    int idx = base + i;
    float dd = 0.f;
    if (idx < T_N) dd = reward[idx] + GAMMA * v1[idx] - v0[idx];
    d[i] = dd;
    s += w * dd;
    w *= C_GL;
  }
  const float W8 = w;
  __shared__ float Ss[256], Sw[256];
  Ss[k] = s; Sw[k] = W8;
  __syncthreads();
  for (int dd = 1; dd < 256; dd <<= 1) {
    bool has = (k + dd) < 256;
    float ns = 0.f, nw = 0.f;
    if (has) { ns = Ss[k] + Sw[k] * Ss[k + dd]; nw = Sw[k] * Sw[k + dd]; }
    __syncthreads();
    if (has) { Ss[k] = ns; Sw[k] = nw; }
    __syncthreads();
  }
  float g = (k < 255) ? Ss[k + 1] : 0.f;
  float sa = 0.f, sq = 0.f;
  if (k < 128) {
#pragma unroll
    for (int i = 7; i >= 0; --i) {
      g = d[i] + C_GL * g;
      float a = g - v0[base + i];
      adv[base + i] = a;
      sa += a; sq += a * a;
    }
  }
  __syncthreads();
  Ss[k] = sa; Sw[k] = sq;
  __syncthreads();
  for (int off = 128; off > 0; off >>= 1) {
    if (k < off) { Ss[k] += Ss[k + off]; Sw[k] += Sw[k + off]; }
    __syncthreads();
  }
  if (k == 0) {
    atomicAdd(&accs[0], Ss[0]);                 // Σ adv
    atomicAdd(&accs[1], Sw[0]);                 // Σ adv² (= critic_loss)
  }
}

// ---------------------------------------------------------------- actor loss (+ final sum, last-block)
__global__ __launch_bounds__(256) void k_loss(
    const float* __restrict__ adv, const float* __restrict__ ratio,
    float* __restrict__ accs, float* __restrict__ out) {
  int t = blockIdx.x * 256 + threadIdx.x;
  float sum  = accs[0];
  float mean = sum * (1.f / (float)T_N);
  float var  = (accs[1] - sum * mean) / (float)(T_N - 1);
  float inv  = 1.f / (sqrtf(var) + 1e-7f);
  float a = (adv[t] - mean) * inv;
  float r = ratio[t];
  float rc = fminf(fmaxf(r, 1.f - EPS_C), 1.f + EPS_C);
  float term = -fminf(r * a, rc * a);
  __shared__ float red[256];
  int k = threadIdx.x;
  red[k] = term;
  __syncthreads();
  for (int off = 128; off > 0; off >>= 1) {
    if (k < off) red[k] += red[k + off];
    __syncthreads();
  }
  if (k == 0) {
    atomicAdd(&accs[2], red[0]);
    __threadfence();
    unsigned int old = atomicAdd((unsigned int*)&accs[3], 1u);
    if (old == (unsigned int)(gridDim.x - 1)) {
      __threadfence();
      volatile float* va = (volatile float*)accs;
      out[0] = va[2] + va[1];                   // actor_loss + critic_loss
    }
  }
}

// ---------------------------------------------------------------- launch
extern "C" void kernel_launch(void* const* d_in, const int* in_sizes, int n_in,
                              void* d_out, int out_size, void* d_ws, size_t ws_size,
                              hipStream_t stream) {
  const float* state      = (const float*)d_in[0];
  const float* next_state = (const float*)d_in[1];
  const float* action     = (const float*)d_in[2];
  const float* beta_lp    = (const float*)d_in[3];
  const float* reward     = (const float*)d_in[4];
  const float* W1   = (const float*)d_in[5];
  const float* b1   = (const float*)d_in[6];
  const float* Wmu  = (const float*)d_in[7];
  const float* bmu  = (const float*)d_in[8];
  const float* Wlv  = (const float*)d_in[9];
  const float* blv  = (const float*)d_in[10];
  const float* Wc1  = (const float*)d_in[11];
  const float* bc1  = (const float*)d_in[12];
  const float* Wc2  = (const float*)d_in[13];
  const float* bc2  = (const float*)d_in[14];

  char* ws = (char*)d_ws;
  size_t o = 0;
  unsigned short* Wc1Ts = (unsigned short*)(ws + o); o += 65536;
  unsigned short* W1Ts  = (unsigned short*)(ws + o); o += 65536;
  unsigned short* H1    = (unsigned short*)(ws + o); o += 8192;
  float* v0    = (float*)(ws + o); o += (size_t)T_N * 4;
  float* v1    = (float*)(ws + o); o += (size_t)T_N * 4;
  float* ratio = (float*)(ws + o); o += (size_t)T_N * 4;
  float* adv   = (float*)(ws + o); o += (size_t)T_N * 4;
  float* accs  = (float*)(ws + o); o += 256;

  hipMemsetAsync(accs, 0, 32, stream);

  k_prep<<<272, 256, 0, stream>>>(Wc1, W1, Wmu, Wlv, Wc1Ts, W1Ts, H1);

  k_state<<<(T_N / 32) / ST_TPB, 512, 0, stream>>>(
      state, action, beta_lp, Wc1Ts, W1Ts, H1, bc1, b1, Wc2, bc2, bmu, blv,
      v0, ratio);
  k_next<<<(T_N / 32) / NX_TPB, 256, 0, stream>>>(
      next_state, Wc1Ts, bc1, Wc2, bc2, v1);
  k_gae<<<256, 256, 0, stream>>>(reward, v0, v1, adv, accs);
  k_loss<<<T_N / 256, 256, 0, stream>>>(adv, ratio, accs, (float*)d_out);
}